// Round 1
// baseline (451.544 us; speedup 1.0000x reference)
//
#include <hip/hip_runtime.h>
#include <stdint.h>

typedef unsigned short u16;

#define S_ 4096
#define B_ 8
#define H_ 1024
#define F_ 1024
#define M_ (S_ * B_)   // 32768
#define N_ F_          // 1024
#define K_ H_          // 1024

#define BM 256
#define BN 256
#define BK 64
#define NT (K_ / BK)   // 16 K-tiles

typedef short short8 __attribute__((ext_vector_type(8)));
typedef float floatx4 __attribute__((ext_vector_type(4)));

// RNE float -> bf16 bits (values are well-behaved: no NaN/Inf in this problem)
__device__ __forceinline__ u16 f2bf(float f) {
    union { float f; uint32_t u; } c;
    c.f = f;
    uint32_t u = c.u;
    uint32_t r = (u + 0x7fffu + ((u >> 16) & 1u)) >> 16;
    return (u16)r;
}

// async 16B/lane global -> LDS (dest = wave-uniform base + lane*16)
__device__ __forceinline__ void async_load16(const void* gptr, void* lptr) {
    __builtin_amdgcn_global_load_lds(
        (const __attribute__((address_space(1))) uint32_t*)gptr,
        (__attribute__((address_space(3))) uint32_t*)lptr,
        16 /*size*/, 0 /*offset*/, 0 /*aux*/);
}

// ---------------------------------------------------------------------------
// Kernel 1: transpose + cast W (K_ x N_ fp32, row-major) -> Bt (N_ x K_ bf16)
// (unchanged, verified)
// ---------------------------------------------------------------------------
__global__ __launch_bounds__(256) void transpose_cast_kernel(
    const float* __restrict__ w, u16* __restrict__ bt)
{
    __shared__ float tile[32][33];
    const int tx = threadIdx.x;  // 0..31
    const int ty = threadIdx.y;  // 0..7
    const int n0 = blockIdx.x * 32;
    const int k0 = blockIdx.y * 32;
#pragma unroll
    for (int j = 0; j < 4; ++j)
        tile[ty + j * 8][tx] = w[(size_t)(k0 + ty + j * 8) * N_ + n0 + tx];
    __syncthreads();
#pragma unroll
    for (int j = 0; j < 4; ++j)
        bt[(size_t)(n0 + ty + j * 8) * K_ + k0 + tx] =
            f2bf(tile[tx][ty + j * 8]);
}

// ---------------------------------------------------------------------------
// Kernel 2: LayerNorm, one WAVE per row (64 lanes x 16 floats = 1024).
// No LDS, no __syncthreads; butterfly shfl_xor reduce; grid-stride at 2048
// blocks (G11: avoid 32768-block dispatch). scale/bias hoisted (row-invariant).
// ---------------------------------------------------------------------------
#define LN_BLOCKS 2048
__global__ __launch_bounds__(256) void ln_kernel(
    const float* __restrict__ x, const float* __restrict__ scale,
    const float* __restrict__ bias, float* __restrict__ ln_out,
    u16* __restrict__ ln_bf16)
{
    const int lane = threadIdx.x & 63;
    const int wid  = (blockIdx.x << 2) | (threadIdx.x >> 6);  // global wave id
    const int nwaves = LN_BLOCKS * 4;                          // 8192

    float4 sc[4], bi[4];
#pragma unroll
    for (int j = 0; j < 4; ++j) {
        sc[j] = reinterpret_cast<const float4*>(scale)[j * 64 + lane];
        bi[j] = reinterpret_cast<const float4*>(bias)[j * 64 + lane];
    }

    for (int row = wid; row < M_; row += nwaves) {
        const float4* xr = reinterpret_cast<const float4*>(x + (size_t)row * H_);
        float4 v[4];
        float s = 0.f, sq = 0.f;
#pragma unroll
        for (int j = 0; j < 4; ++j) {
            v[j] = xr[j * 64 + lane];
            s  += v[j].x + v[j].y + v[j].z + v[j].w;
            sq += v[j].x * v[j].x + v[j].y * v[j].y +
                  v[j].z * v[j].z + v[j].w * v[j].w;
        }
#pragma unroll
        for (int off = 32; off >= 1; off >>= 1) {
            s  += __shfl_xor(s, off, 64);
            sq += __shfl_xor(sq, off, 64);
        }
        const float mu   = s * (1.0f / H_);
        const float var  = sq * (1.0f / H_) - mu * mu;
        const float rstd = rsqrtf(var + 1e-6f);

        float4* yr = reinterpret_cast<float4*>(ln_out + (size_t)row * H_);
        ushort4* hr = reinterpret_cast<ushort4*>(ln_bf16 + (size_t)row * H_);
#pragma unroll
        for (int j = 0; j < 4; ++j) {
            float4 y;
            y.x = (v[j].x - mu) * rstd * sc[j].x + bi[j].x;
            y.y = (v[j].y - mu) * rstd * sc[j].y + bi[j].y;
            y.z = (v[j].z - mu) * rstd * sc[j].z + bi[j].z;
            y.w = (v[j].w - mu) * rstd * sc[j].w + bi[j].w;
            yr[j * 64 + lane] = y;
            ushort4 h;
            h.x = f2bf(y.x); h.y = f2bf(y.y); h.z = f2bf(y.z); h.w = f2bf(y.w);
            hr[j * 64 + lane] = h;
        }
    }
}

// ---------------------------------------------------------------------------
// Kernel 3: GEMM C = A * Bt^T.  256x256 tile, BK=64, 8 waves (2M x 4N),
// per-wave 128x64 output via 8x4 x mfma_f32_16x16x32_bf16.
//
// Depth-1 software pipeline (T3-min): double-buffered LDS (128 KiB), raw
// s_barrier + explicit s_waitcnt (ONE barrier per K-tile, no __syncthreads
// vmcnt(0)-before-issue drain). Tile t+2 is staged right after the barrier
// that retires tile t's reads, so its global_load_lds gets a full K-tile of
// compute (~600 cyc) to land before the drain that precedes its use.
//
// LDS XOR chunk swizzle (verified in previous version): slot (row, c) holds
// global 16B-chunk (c ^ (row & 7)); implemented by pre-swizzling the global
// source address (global_load_lds dest is linear base + lane*16).
//
// Grid 512 = 128 M-tiles x 4 N-tiles, XCD swizzle: the 4 N-tiles sharing an
// A-panel have equal (bid & 7) -> same XCD under round-robin.
// ---------------------------------------------------------------------------
__global__ __launch_bounds__(512, 2) void gemm_bt_kernel(
    const u16* __restrict__ A, const u16* __restrict__ Bt,
    float* __restrict__ C)
{
    __shared__ __align__(16) u16 As[2][BM * BK];   // 2 x 32 KiB
    __shared__ __align__(16) u16 Bs[2][BN * BK];   // 2 x 32 KiB

    const int tid  = threadIdx.x;
    const int wid  = tid >> 6;        // 0..7
    const int lane = tid & 63;
    const int wm   = wid >> 2;        // 0..1  (M half)
    const int wn   = wid & 3;         // 0..3  (N quarter)

    const int bid  = blockIdx.x;
    const int bx   = (bid >> 3) & 3;
    const int by   = ((bid >> 5) << 3) | (bid & 7);
    const int row0 = by * BM;
    const int col0 = bx * BN;

    floatx4 acc[8][4];
#pragma unroll
    for (int i = 0; i < 8; ++i)
#pragma unroll
        for (int j = 0; j < 4; ++j) acc[i][j] = (floatx4)0.0f;

    // staging: per call, wave fills 8 rows (64 lanes * 16B = 8 x 128B rows);
    // 4 calls/operand cover 256 rows. lane (r=lane>>3, c=lane&7) fetches
    // global chunk (c ^ r) of its row (XOR swizzle via global address).
    const int srow   = (wid << 3) | (lane >> 3);       // 0..63 per 64-row group
    const int schunk = (lane & 7) ^ (srow & 7);
    const u16* Ag = A  + (size_t)(row0 + srow) * K_ + schunk * 8;
    const u16* Bg = Bt + (size_t)(col0 + srow) * K_ + schunk * 8;

#define STAGE(buf, kt) do {                                                   \
    const size_t koff_ = (size_t)(kt) * BK;                                   \
    _Pragma("unroll")                                                         \
    for (int i_ = 0; i_ < 4; ++i_) {                                          \
        async_load16(Ag + (size_t)(i_ * 64) * K_ + koff_,                     \
                     (char*)As[buf] + (size_t)(i_ * 64 + (wid << 3)) * 128);  \
        async_load16(Bg + (size_t)(i_ * 64) * K_ + koff_,                     \
                     (char*)Bs[buf] + (size_t)(i_ * 64 + (wid << 3)) * 128);  \
    }                                                                         \
} while (0)

    // prologue: stage tiles 0 and 1, wait for tile 0 only (counted vmcnt)
    STAGE(0, 0);
    STAGE(1, 1);
    asm volatile("s_waitcnt vmcnt(8)" ::: "memory");
    __builtin_amdgcn_s_barrier();

    int cur = 0;
    for (int t = 0; t < NT; ++t) {
        // ---- compute K-tile t from buffer cur ----
        short8 bfrag[4][2];
#pragma unroll
        for (int nt = 0; nt < 4; ++nt)
#pragma unroll
            for (int ks = 0; ks < 2; ++ks) {
                const int r  = (wn << 6) | (nt << 4) | (lane & 15);
                const int q  = (ks << 2) | (lane >> 4);
                const int cc = q ^ (r & 7);
                bfrag[nt][ks] = *reinterpret_cast<const short8*>(
                    (const char*)Bs[cur] + (size_t)r * 128 + cc * 16);
            }
#pragma unroll
        for (int mp = 0; mp < 4; ++mp) {   // 4 sub-phases of 2 M-frags each
            short8 afrag[2][2];
#pragma unroll
            for (int mi = 0; mi < 2; ++mi)
#pragma unroll
                for (int ks = 0; ks < 2; ++ks) {
                    const int mt = mp * 2 + mi;
                    const int r  = (wm << 7) | (mt << 4) | (lane & 15);
                    const int q  = (ks << 2) | (lane >> 4);
                    const int cc = q ^ (r & 7);
                    afrag[mi][ks] = *reinterpret_cast<const short8*>(
                        (const char*)As[cur] + (size_t)r * 128 + cc * 16);
                }
            __builtin_amdgcn_s_setprio(1);
#pragma unroll
            for (int mi = 0; mi < 2; ++mi)
#pragma unroll
                for (int nt = 0; nt < 4; ++nt)
#pragma unroll
                    for (int ks = 0; ks < 2; ++ks)
                        acc[mp * 2 + mi][nt] =
                            __builtin_amdgcn_mfma_f32_16x16x32_bf16(
                                afrag[mi][ks], bfrag[nt][ks],
                                acc[mp * 2 + mi][nt], 0, 0, 0);
            __builtin_amdgcn_s_setprio(0);
        }

        if (t == NT - 1) break;
        // retire this wave's reads of buf[cur] (lgkm) and tile t+1's staged
        // loads (vm, issued one full K-tile ago); then one barrier publishes
        // buf[cur^1] and frees buf[cur] for tile t+2.
        asm volatile("s_waitcnt vmcnt(0) lgkmcnt(0)" ::: "memory");
        __builtin_amdgcn_s_barrier();
        if (t + 2 < NT) STAGE(cur, t + 2);
        cur ^= 1;
    }
#undef STAGE

    // epilogue: C/D layout col = lane&15, row = (lane>>4)*4 + reg
#pragma unroll
    for (int mt = 0; mt < 8; ++mt) {
#pragma unroll
        for (int nt = 0; nt < 4; ++nt) {
            const int r0 = row0 + (wm << 7) + (mt << 4) + ((lane >> 4) << 2);
            const int c  = col0 + (wn << 6) + (nt << 4) + (lane & 15);
#pragma unroll
            for (int r = 0; r < 4; ++r)
                C[(size_t)(r0 + r) * N_ + c] = acc[mt][nt][r];
        }
    }
}

// ---------------------------------------------------------------------------
extern "C" void kernel_launch(void* const* d_in, const int* in_sizes, int n_in,
                              void* d_out, int out_size, void* d_ws, size_t ws_size,
                              hipStream_t stream) {
    const float* x      = (const float*)d_in[0];   // (S,B,H)
    const float* scale  = (const float*)d_in[1];   // (H,)
    const float* lnbias = (const float*)d_in[2];   // (H,)
    const float* weight = (const float*)d_in[3];   // (H,F)

    float* out    = (float*)d_out;                     // (S,B,F)
    float* ln_out = (float*)d_out + (size_t)M_ * N_;   // (S,B,H)

    // workspace: [A bf16: M_*K_ u16 = 64 MiB][Bt bf16: N_*K_ u16 = 2 MiB]
    u16* ln_bf16 = (u16*)d_ws;
    u16* bt      = (u16*)d_ws + (size_t)M_ * K_;

    transpose_cast_kernel<<<dim3(N_ / 32, K_ / 32), dim3(32, 8), 0, stream>>>(
        weight, bt);
    ln_kernel<<<LN_BLOCKS, 256, 0, stream>>>(x, scale, lnbias, ln_out, ln_bf16);
    gemm_bt_kernel<<<(M_ / BM) * (N_ / BN), 512, 0, stream>>>(ln_bf16, bt, out);
}